// Round 3
// baseline (682.116 us; speedup 1.0000x reference)
//
#include <hip/hip_runtime.h>
#include <stdint.h>

// Layered Bayesian net marginal chain.
// 63 sequential layers, M=16384 nodes, K=4 parents, C=16 CPT entries.
// Strategy: ONE persistent kernel (16384 threads = 1/node) + custom
// device-wide barrier per layer in d_ws. Compute & BW are trivial
// (~0.5M transc + 1.3MB per layer); the 63 grid syncs dominate, so we
// avoid 63 kernel launches and hide input-load latency inside the
// barrier spin window.

namespace {
constexpr int kLayers  = 63;     // hidden layers
constexpr int kM       = 16384;  // nodes per layer
constexpr int kBlocks  = 64;
constexpr int kThreads = 256;    // kBlocks*kThreads == kM, 1 thread per node
constexpr unsigned kBarStride = 16;  // uint32 per barrier slot = 64B line
}

__global__ void zero_bars_kernel(uint32_t* __restrict__ bar, int n) {
  int i = blockIdx.x * blockDim.x + threadIdx.x;
  if (i < n) bar[i] = 0u;
}

__device__ __forceinline__ float fsig(float x) {
  // sigmoid; fp32 fast-math is far inside the 1.8e-2 abs threshold
  return __fdividef(1.0f, 1.0f + __expf(-x));
}

__global__ __launch_bounds__(kThreads) void bayes_chain_kernel(
    const float* __restrict__ root_logits,   // [kM]
    const float* __restrict__ layer_logits,  // [kLayers][kM][16]
    const int*   __restrict__ parent_idx,    // [kLayers][kM][4]
    float* __restrict__ out,                 // [kLayers+1][kM]
    uint32_t* __restrict__ bar)              // [kLayers][kBarStride]
{
  const int m = blockIdx.x * kThreads + threadIdx.x;

  // ---- row 0: root marginals ----
  out[m] = fsig(root_logits[m]);

  const float4* lg4 = reinterpret_cast<const float4*>(layer_logits)
                      + (size_t)m * 4;                 // 16 floats/node
  const int4*   pi4 = reinterpret_cast<const int4*>(parent_idx) + m;

  const float* prev = out;
  float*       cur  = out + kM;

  for (int t = 0; t < kLayers; ++t) {
    // ================= grid barrier t =================
    // Release: our stores (row t) must be agent-visible before arrive.
    // __threadfence() on gfx950 = agent-scope fence -> waitcnt + L2
    // writeback past the XCD (cross-XCD L2s are NOT coherent, G16).
    __threadfence();
    __syncthreads();
    if (threadIdx.x == 0) {
      __hip_atomic_fetch_add(&bar[t * kBarStride], 1u,
                             __ATOMIC_RELAXED, __HIP_MEMORY_SCOPE_AGENT);
    }
    // Prefetch THIS layer's read-only inputs between arrive and spin:
    // latency hides under the barrier wait; read-only data can't be stale.
    const size_t lgo = (size_t)t * kM * 4;
    float4 c0 = lg4[lgo + 0];
    float4 c1 = lg4[lgo + 1];
    float4 c2 = lg4[lgo + 2];
    float4 c3 = lg4[lgo + 3];
    int4 idx  = pi4[(size_t)t * kM];
    if (threadIdx.x == 0) {
      while (__hip_atomic_load(&bar[t * kBarStride],
                               __ATOMIC_RELAXED,
                               __HIP_MEMORY_SCOPE_AGENT) < (unsigned)kBlocks) {
        __builtin_amdgcn_s_sleep(2);
      }
    }
    __syncthreads();
    // Acquire: invalidate L1/L2 so gathers below see remote rows.
    __threadfence();
    // ==================================================

    // gather parent marginals from row t (64KB, L2/L3-hot)
    float p0 = prev[idx.x];
    float p1 = prev[idx.y];
    float p2 = prev[idx.z];
    float p3 = prev[idx.w];
    float q0 = 1.0f - p0, q1 = 1.0f - p1, q2 = 1.0f - p2, q3 = 1.0f - p3;

    // CPT probabilities, c = 0..15 contiguous
    float s0 = fsig(c0.x), s1 = fsig(c0.y), s2 = fsig(c0.z), s3 = fsig(c0.w);
    float s4 = fsig(c1.x), s5 = fsig(c1.y), s6 = fsig(c1.z), s7 = fsig(c1.w);
    float s8 = fsig(c2.x), s9 = fsig(c2.y), sa = fsig(c2.z), sb = fsig(c2.w);
    float sc = fsig(c3.x), sd = fsig(c3.y), se = fsig(c3.z), sf = fsig(c3.w);

    // Config weights factorize (MSB-first: c = b0 b1 b2 b3, bk = bit of
    // parent k). weight[c] = f0(b0) f1(b1) f2(b2) f3(b3), fk(1)=pk, fk(0)=qk.
    float w0 = q2 * q3, w1 = q2 * p3, w2 = p2 * q3, w3 = p2 * p3;  // (b2,b3)
    float i0 = s0 * w0 + s1 * w1 + s2 * w2 + s3 * w3;   // (b0,b1)=(0,0)
    float i1 = s4 * w0 + s5 * w1 + s6 * w2 + s7 * w3;   // (0,1)
    float i2 = s8 * w0 + s9 * w1 + sa * w2 + sb * w3;   // (1,0)
    float i3 = sc * w0 + sd * w1 + se * w2 + sf * w3;   // (1,1)
    float marg = (q0 * q1) * i0 + (q0 * p1) * i1
               + (p0 * q1) * i2 + (p0 * p1) * i3;

    cur[m] = marg;
    prev = cur;
    cur += kM;
  }
}

extern "C" void kernel_launch(void* const* d_in, const int* in_sizes, int n_in,
                              void* d_out, int out_size, void* d_ws, size_t ws_size,
                              hipStream_t stream) {
  const float* root = (const float*)d_in[0];
  const float* lg   = (const float*)d_in[1];
  const int*   pidx = (const int*)d_in[2];
  float* out        = (float*)d_out;
  uint32_t* bar     = (uint32_t*)d_ws;   // 63 * 64B = 4KB of scratch

  // Zero barrier counters every launch (d_ws is poisoned once, never
  // re-poisoned between graph replays -> must re-init ourselves).
  const int nbar = kLayers * (int)kBarStride;
  zero_bars_kernel<<<(nbar + 255) / 256, 256, 0, stream>>>(bar, nbar);

  bayes_chain_kernel<<<kBlocks, kThreads, 0, stream>>>(root, lg, pidx, out, bar);
}

// Round 4
// 243.732 us; speedup vs baseline: 2.7986x; 2.7986x over previous
//
#include <hip/hip_runtime.h>
#include <stdint.h>

// Layered Bayesian net marginal chain: 63 sequential layers, M=16384 nodes,
// K=4 parents, C=16 CPT entries per node.
//
// R2 -> R3: the 10.8us/layer cost was __threadfence() = agent seq_cst fence
// = buffer_wbl2 + buffer_inv (FULL-L2 writeback/invalidate) twice per block
// per layer on gfx950 (non-coherent per-XCD L2s). Replace cache-wide fences
// with per-access coherence: marginals are stored/gathered with relaxed
// AGENT-scope atomics (sc0 sc1: write-through / L1-L2-bypass, coherent at
// L3), ordering enforced by s_waitcnt vmcnt(0) before the barrier arrive.
// Read-only logits/idx keep normal cached loads. Zero cache-maintenance ops.

namespace {
constexpr int kLayers  = 63;     // hidden layers
constexpr int kM       = 16384;  // nodes per layer
constexpr int kBlocks  = 64;
constexpr int kThreads = 256;    // kBlocks*kThreads == kM, 1 thread per node
constexpr unsigned kBarStride = 16;  // uint32 per barrier slot = 64B line
}

__global__ void zero_bars_kernel(uint32_t* __restrict__ bar, int n) {
  int i = blockIdx.x * blockDim.x + threadIdx.x;
  if (i < n) bar[i] = 0u;
}

__device__ __forceinline__ float fsig(float x) {
  // sigmoid; fp32 fast-math is far inside the 1.8e-2 abs threshold
  return __fdividef(1.0f, 1.0f + __expf(-x));
}

// Agent-scope (device-coherent) accesses: bypass the non-coherent per-XCD
// L1/L2 copies, hit the coherence point directly. No cache-wide maintenance.
__device__ __forceinline__ void agent_store(float* p, float v) {
  __hip_atomic_store(p, v, __ATOMIC_RELAXED, __HIP_MEMORY_SCOPE_AGENT);
}
__device__ __forceinline__ float agent_load(const float* p) {
  return __hip_atomic_load(p, __ATOMIC_RELAXED, __HIP_MEMORY_SCOPE_AGENT);
}

__global__ __launch_bounds__(kThreads) void bayes_chain_kernel(
    const float* __restrict__ root_logits,   // [kM]
    const float* __restrict__ layer_logits,  // [kLayers][kM][16]
    const int*   __restrict__ parent_idx,    // [kLayers][kM][4]
    float* __restrict__ out,                 // [kLayers+1][kM]
    uint32_t* __restrict__ bar)              // [kLayers][kBarStride]
{
  const int m = blockIdx.x * kThreads + threadIdx.x;

  // ---- row 0: root marginals (write-through so layer 1's gathers see it) ----
  agent_store(&out[m], fsig(root_logits[m]));

  const float4* lg4 = reinterpret_cast<const float4*>(layer_logits)
                      + (size_t)m * 4;                 // 16 floats/node
  const int4*   pi4 = reinterpret_cast<const int4*>(parent_idx) + m;

  const float* prev = out;
  float*       cur  = out + kM;

  for (int t = 0; t < kLayers; ++t) {
    // ================= grid barrier t (fence-free) =================
    // Drain this wave's write-through stores: on ack they are at the
    // coherence point, so anything issued after is globally ordered later.
    asm volatile("s_waitcnt vmcnt(0)" ::: "memory");
    __builtin_amdgcn_sched_barrier(0);
    __syncthreads();                       // all 4 waves' stores drained
    if (threadIdx.x == 0) {
      __hip_atomic_fetch_add(&bar[t * kBarStride], 1u,
                             __ATOMIC_RELAXED, __HIP_MEMORY_SCOPE_AGENT);
    }
    // Prefetch THIS layer's read-only inputs (normal cached loads) in the
    // arrive->spin window: latency hides under the global arrival wait.
    const size_t lgo = (size_t)t * kM * 4;
    float4 c0 = lg4[lgo + 0];
    float4 c1 = lg4[lgo + 1];
    float4 c2 = lg4[lgo + 2];
    float4 c3 = lg4[lgo + 3];
    int4 idx  = pi4[(size_t)t * kM];
    // All threads poll (wave-uniform address -> one broadcast load per wave);
    // each wave proceeds as soon as it observes the full count.
    while (__hip_atomic_load(&bar[t * kBarStride],
                             __ATOMIC_RELAXED,
                             __HIP_MEMORY_SCOPE_AGENT) < (unsigned)kBlocks) {
      __builtin_amdgcn_s_sleep(1);
    }
    // Keep the gathers below from being hoisted above the spin exit.
    asm volatile("" ::: "memory");
    __builtin_amdgcn_sched_barrier(0);
    // ===============================================================

    // gather parent marginals from row t, straight from the coherence point
    float p0 = agent_load(&prev[idx.x]);
    float p1 = agent_load(&prev[idx.y]);
    float p2 = agent_load(&prev[idx.z]);
    float p3 = agent_load(&prev[idx.w]);
    float q0 = 1.0f - p0, q1 = 1.0f - p1, q2 = 1.0f - p2, q3 = 1.0f - p3;

    // CPT probabilities, c = 0..15 contiguous
    float s0 = fsig(c0.x), s1 = fsig(c0.y), s2 = fsig(c0.z), s3 = fsig(c0.w);
    float s4 = fsig(c1.x), s5 = fsig(c1.y), s6 = fsig(c1.z), s7 = fsig(c1.w);
    float s8 = fsig(c2.x), s9 = fsig(c2.y), sa = fsig(c2.z), sb = fsig(c2.w);
    float sc = fsig(c3.x), sd = fsig(c3.y), se = fsig(c3.z), sf = fsig(c3.w);

    // Config weights factorize (MSB-first: c = b0 b1 b2 b3, bk = bit of
    // parent k). weight[c] = f0(b0) f1(b1) f2(b2) f3(b3), fk(1)=pk, fk(0)=qk.
    float w0 = q2 * q3, w1 = q2 * p3, w2 = p2 * q3, w3 = p2 * p3;  // (b2,b3)
    float i0 = s0 * w0 + s1 * w1 + s2 * w2 + s3 * w3;   // (b0,b1)=(0,0)
    float i1 = s4 * w0 + s5 * w1 + s6 * w2 + s7 * w3;   // (0,1)
    float i2 = s8 * w0 + s9 * w1 + sa * w2 + sb * w3;   // (1,0)
    float i3 = sc * w0 + sd * w1 + se * w2 + sf * w3;   // (1,1)
    float marg = (q0 * q1) * i0 + (q0 * p1) * i1
               + (p0 * q1) * i2 + (p0 * p1) * i3;

    agent_store(&cur[m], marg);   // write-through: next layer gathers it
    prev = cur;
    cur += kM;
  }
}

extern "C" void kernel_launch(void* const* d_in, const int* in_sizes, int n_in,
                              void* d_out, int out_size, void* d_ws, size_t ws_size,
                              hipStream_t stream) {
  const float* root = (const float*)d_in[0];
  const float* lg   = (const float*)d_in[1];
  const int*   pidx = (const int*)d_in[2];
  float* out        = (float*)d_out;
  uint32_t* bar     = (uint32_t*)d_ws;   // 63 * 64B = 4KB of scratch

  // Zero barrier counters every launch (d_ws is poisoned once, never
  // re-poisoned between graph replays -> must re-init ourselves).
  const int nbar = kLayers * (int)kBarStride;
  zero_bars_kernel<<<(nbar + 255) / 256, 256, 0, stream>>>(bar, nbar);

  bayes_chain_kernel<<<kBlocks, kThreads, 0, stream>>>(root, lg, pidx, out, bar);
}